// Round 10
// baseline (38.160 us; speedup 1.0000x reference)
//
#include <hip/hip_runtime.h>
#include <math.h>

#define EPS 1e-6f
#define LOG2E 1.4426950408889634f
// Schraudolph exp2 bias: (127 + c)*2^23, c tuned for zero-mean relative error
// over uniform mantissa fraction (range ~[-5.7%, +2.0%]). Confirmed R8.
#define SCHRAUD_K 1064878421.0f

constexpr int TB  = 256;   // threads/block (4 waves)
constexpr int TD  = 256;   // dense tile dim (1 i-row/thread, TD j's in LDS)
constexpr int EPT = 8;     // edges per thread

// exp2(-rp) ~ Schraudolph: 2 full-rate VALU ops (fma + cvt) vs 8-cyc trans.
__device__ __forceinline__ float fast_exp2_neg(float rp) {
    return __int_as_float((int)fmaf(rp, -8388608.0f, SCHRAUD_K));
}

// Single compute kernel + 16B memset node. Blocks [0, ne): edge chunks.
// Blocks [ne, ne+nd): dense triangular tiles. Each block adds its pre-weighted
// partial into ws->sum via HW f64 atomic (relaxed, agent scope — NO
// threadfence: R5 showed the fence's L2 writeback costs ~10us). The returned
// old value feeds an asm barrier, forcing vmcnt(0) (RMW complete at coherent
// point) before the done-counter atomic; so cnt==np-1 implies all sum-adds
// are globally visible. Last block reads the total and writes out[0].
// (f64 add reordering ~1e-13 rel — invisible after float cast.)
//
// Dense inner loop (R8, best known): per pair {sub,sub,mul,fma} + exact
// v_sqrt + {fma,cvt} schraudolph + fma(acc) = 22 issue-cyc/wave-j.
// R9 lesson: ext_vector float2 "pk" rewrite regressed — keep scalar.
__global__ void __launch_bounds__(TB) k_fused(
    const float2* __restrict__ Z, const float* __restrict__ gamma,
    const int* __restrict__ ei, const int* __restrict__ ej,
    double* __restrict__ gsum, unsigned* __restrict__ cnt,
    float* __restrict__ out, int n, int nb, int ne, int e)
{
    __shared__ float4 sXY[TD / 2];   // (x_2k, x_2k+1, y_2k, y_2k+1) * LOG2E
    __shared__ float2 sW[TD / 2];    // (exp(g_2k), exp(g_2k+1))
    __shared__ float wsum[TB / 64];
    const int bx = blockIdx.x;
    const int np = gridDim.x;
    float acc = 0.f;
    float blockw = 1.f;

    if (bx >= ne) {
        // ---- dense role: decode triangular index -> (a,b), b >= a ----
        const int t = bx - ne;
        auto before = [nb](int x) { return x * nb - (x * (x - 1)) / 2; };
        int a = (int)(((2 * nb + 1) -
                       sqrtf((float)((2 * nb + 1) * (2 * nb + 1) - 8 * t))) * 0.5f);
        if (a < 0) a = 0;
        if (a > nb - 1) a = nb - 1;
        while (before(a + 1) <= t) ++a;
        while (before(a) > t) --a;
        const int b = a + (t - before(a));

        const int j0 = b * TD;

        if (threadIdx.x < TD / 2) {
            const int k  = threadIdx.x;
            const int j1 = j0 + 2 * k, j2 = j1 + 1;
            float4 xy;
            float2 w;
            if (j2 < n) {
                float4 zz = *(const float4*)(&Z[j1]);   // (x1,y1,x2,y2)
                float2 gg = *(const float2*)(&gamma[j1]);
                xy = make_float4(zz.x * LOG2E, zz.z * LOG2E,
                                 zz.y * LOG2E, zz.w * LOG2E);
                w  = make_float2(__expf(gg.x), __expf(gg.y));
            } else {
                int c1 = j1 < n ? j1 : n - 1;
                int c2 = j2 < n ? j2 : n - 1;
                float2 z1 = Z[c1], z2 = Z[c2];
                xy = make_float4(z1.x * LOG2E, z2.x * LOG2E,
                                 z1.y * LOG2E, z2.y * LOG2E);
                w  = make_float2(j1 < n ? __expf(gamma[c1]) : 0.f,
                                 j2 < n ? __expf(gamma[c2]) : 0.f);
            }
            sXY[k] = xy;
            sW[k]  = w;
        }
        __syncthreads();

        const int i = a * TD + threadIdx.x;
        if (i < n) {
            float2 zi = Z[i];
            const float ax = (zi.x + EPS) * LOG2E;
            const float ay = (zi.y + EPS) * LOG2E;
            float acc0 = 0.f, acc1 = 0.f;
            #pragma unroll 8
            for (int k = 0; k < TD / 2; ++k) {
                float4 p = sXY[k];
                float2 w = sW[k];
                float dx0 = ax - p.x, dx1 = ax - p.y;
                float dy0 = ay - p.z, dy1 = ay - p.w;
                float d20 = fmaf(dx0, dx0, dy0 * dy0);  // difference form >= 0
                float d21 = fmaf(dx1, dx1, dy1 * dy1);
                float r0 = __builtin_amdgcn_sqrtf(d20); // exact trans
                float r1 = __builtin_amdgcn_sqrtf(d21);
                acc0 = fmaf(w.x, fast_exp2_neg(r0), acc0);
                acc1 = fmaf(w.y, fast_exp2_neg(r1), acc1);
            }
            acc = acc0 + acc1;
            float egi = __expf(gamma[i]);
            if (a == b) {
                // subtract diag through the SAME approximant so it cancels
                acc -= egi * fast_exp2_neg(1.41421356e-6f * LOG2E);
            }
            acc *= egi;
        }
        blockw = (a == b) ? -0.5f : -1.0f;
    } else {
        // ---- edge role (latency-bound L2 gathers; exact trans) ----
        const long base = ((long)bx * TB + threadIdx.x) * EPT;
        if (base + EPT <= e) {
            int4 ia0 = *(const int4*)(ei + base);
            int4 ia1 = *(const int4*)(ei + base + 4);
            int4 ja0 = *(const int4*)(ej + base);
            int4 ja1 = *(const int4*)(ej + base + 4);
            const int as[EPT] = {ia0.x, ia0.y, ia0.z, ia0.w,
                                 ia1.x, ia1.y, ia1.z, ia1.w};
            const int bs[EPT] = {ja0.x, ja0.y, ja0.z, ja0.w,
                                 ja1.x, ja1.y, ja1.z, ja1.w};
            #pragma unroll
            for (int k = 0; k < EPT; ++k) {
                float2 za = Z[as[k]], zb = Z[bs[k]];
                float dx = za.x - zb.x + EPS;
                float dy = za.y - zb.y + EPS;
                float r = __builtin_amdgcn_sqrtf(fmaf(dx, dx, dy * dy));
                acc += gamma[as[k]] + gamma[bs[k]] - r;
            }
        } else {
            for (int k = 0; k < EPT; ++k) {
                long idx = base + k;
                if (idx < e) {
                    int ai = ei[idx], bi = ej[idx];
                    float2 za = Z[ai], zb = Z[bi];
                    float dx = za.x - zb.x + EPS;
                    float dy = za.y - zb.y + EPS;
                    float r = __builtin_amdgcn_sqrtf(fmaf(dx, dx, dy * dy));
                    acc += gamma[ai] + gamma[bi] - r;
                }
            }
        }
        blockw = 1.f;
    }

    // fixed-order deterministic block reduction
    for (int off = 32; off > 0; off >>= 1) acc += __shfl_down(acc, off, 64);
    const int lane = threadIdx.x & 63, w = threadIdx.x >> 6;
    if (lane == 0) wsum[w] = acc;
    __syncthreads();
    if (threadIdx.x == 0) {
        float s = 0.f;
        #pragma unroll
        for (int k = 0; k < TB / 64; ++k) s += wsum[k];

        // device-scope f64 accumulate (HW global_atomic_add_f64, no fence)
        double old = __hip_atomic_fetch_add(gsum, (double)(blockw * s),
                                            __ATOMIC_RELAXED,
                                            __HIP_MEMORY_SCOPE_AGENT);
        // consume 'old' -> compiler must s_waitcnt vmcnt(0) before this, so
        // our RMW is complete at the coherent point before we signal.
        asm volatile("" :: "v"(old) : "memory");

        unsigned prev = __hip_atomic_fetch_add(cnt, 1u,
                                               __ATOMIC_RELAXED,
                                               __HIP_MEMORY_SCOPE_AGENT);
        if (prev == (unsigned)(np - 1)) {
            // last block: all sum-adds are complete & visible; read and emit
            double tot = __hip_atomic_load(gsum, __ATOMIC_RELAXED,
                                           __HIP_MEMORY_SCOPE_AGENT);
            out[0] = (float)tot;
        }
    }
}

extern "C" void kernel_launch(void* const* d_in, const int* in_sizes, int n_in,
                              void* d_out, int out_size, void* d_ws, size_t ws_size,
                              hipStream_t stream)
{
    const float2* Z     = (const float2*)d_in[0];
    const float*  gamma = (const float*)d_in[1];
    const int*    ei    = (const int*)d_in[2];
    const int*    ej    = (const int*)d_in[3];
    const int n = in_sizes[1];
    const int e = in_sizes[2];
    float* out = (float*)d_out;

    const int nb = (n + TD - 1) / TD;
    const int nd = nb * (nb + 1) / 2;
    const int ne = (e + TB * EPT - 1) / (TB * EPT);
    const int np = ne + nd;

    double*   gsum = (double*)d_ws;
    unsigned* cnt  = (unsigned*)(gsum + 1);

    // ws is poisoned 0xAA once and never re-poisoned between replays:
    // zero sum+cnt every call (single 16B memset node, capture-safe).
    hipMemsetAsync(d_ws, 0, 16, stream);

    hipLaunchKernelGGL(k_fused, dim3(np), dim3(TB), 0, stream,
                       Z, gamma, ei, ej, gsum, cnt, out, n, nb, ne, e);
}

// Round 11
// 25.716 us; speedup vs baseline: 1.4839x; 1.4839x over previous
//
#include <hip/hip_runtime.h>
#include <math.h>

#define EPS 1e-6f
#define LOG2E 1.4426950408889634f
// Schraudolph exp2 bias: (127 + c)*2^23, c tuned for zero-mean relative error
// over uniform mantissa fraction (range ~[-5.7%, +2.0%]). Confirmed R8.
#define SCHRAUD_K 1064878421.0f

constexpr int TB  = 256;   // threads/block (4 waves)
constexpr int TD  = 256;   // dense tile dim (1 i-row/thread, TD j's in LDS)
constexpr int EPT = 16;    // edges per thread (64 gathers in flight)

// exp2(-rp) ~ Schraudolph: 2 full-rate VALU ops (fma + cvt) vs 8-cyc trans.
__device__ __forceinline__ float fast_exp2_neg(float rp) {
    return __int_as_float((int)fmaf(rp, -8388608.0f, SCHRAUD_K));
}

// TWO-KERNEL STRUCTURE — SETTLED. R5/R10 proved any per-block device-scope
// coordination (threadfence or atomics to a shared line) costs ~10us+ on
// MI355X (~2000 serialized RMWs at the coherency point). Do not revisit.
//
// Blocks [0, ne): edge chunks (gathers overlap dense compute).
// Blocks [ne, ne+nd): dense triangular tiles. part[] pre-weighted.
//
// Dense inner loop (R8, settled): per pair {sub,sub,mul,fma} + exact v_sqrt
// (trans, co-issues with other waves' VALU -> non-binding) + {fma,cvt}
// schraudolph + fma(acc) = 7 VALU + 1 trans. R9: pk-rewrite regressed.
// R6: readlane broadcast regressed. R3: dot-expansion NaN'd.
__global__ void __launch_bounds__(TB) k_fused(
    const float2* __restrict__ Z, const float* __restrict__ gamma,
    const int* __restrict__ ei, const int* __restrict__ ej,
    float* __restrict__ part, int n, int nb, int ne, int e)
{
    __shared__ float4 sXY[TD / 2];   // (x_2k, x_2k+1, y_2k, y_2k+1) * LOG2E
    __shared__ float2 sW[TD / 2];    // (exp(g_2k), exp(g_2k+1))
    __shared__ float wsum[TB / 64];
    const int bx = blockIdx.x;
    float acc = 0.f;
    float blockw = 1.f;

    if (bx >= ne) {
        // ---- dense role: decode triangular index -> (a,b), b >= a ----
        const int t = bx - ne;
        auto before = [nb](int x) { return x * nb - (x * (x - 1)) / 2; };
        int a = (int)(((2 * nb + 1) -
                       sqrtf((float)((2 * nb + 1) * (2 * nb + 1) - 8 * t))) * 0.5f);
        if (a < 0) a = 0;
        if (a > nb - 1) a = nb - 1;
        while (before(a + 1) <= t) ++a;
        while (before(a) > t) --a;
        const int b = a + (t - before(a));

        const int j0 = b * TD;

        if (threadIdx.x < TD / 2) {
            const int k  = threadIdx.x;
            const int j1 = j0 + 2 * k, j2 = j1 + 1;
            float4 xy;
            float2 w;
            if (j2 < n) {
                float4 zz = *(const float4*)(&Z[j1]);   // (x1,y1,x2,y2)
                float2 gg = *(const float2*)(&gamma[j1]);
                xy = make_float4(zz.x * LOG2E, zz.z * LOG2E,
                                 zz.y * LOG2E, zz.w * LOG2E);
                w  = make_float2(__expf(gg.x), __expf(gg.y));
            } else {
                int c1 = j1 < n ? j1 : n - 1;
                int c2 = j2 < n ? j2 : n - 1;
                float2 z1 = Z[c1], z2 = Z[c2];
                xy = make_float4(z1.x * LOG2E, z2.x * LOG2E,
                                 z1.y * LOG2E, z2.y * LOG2E);
                w  = make_float2(j1 < n ? __expf(gamma[c1]) : 0.f,
                                 j2 < n ? __expf(gamma[c2]) : 0.f);
            }
            sXY[k] = xy;
            sW[k]  = w;
        }
        __syncthreads();

        const int i = a * TD + threadIdx.x;
        if (i < n) {
            float2 zi = Z[i];
            const float ax = (zi.x + EPS) * LOG2E;
            const float ay = (zi.y + EPS) * LOG2E;
            float acc0 = 0.f, acc1 = 0.f;
            #pragma unroll 8
            for (int k = 0; k < TD / 2; ++k) {
                float4 p = sXY[k];
                float2 w = sW[k];
                float dx0 = ax - p.x, dx1 = ax - p.y;
                float dy0 = ay - p.z, dy1 = ay - p.w;
                float d20 = fmaf(dx0, dx0, dy0 * dy0);  // difference form >= 0
                float d21 = fmaf(dx1, dx1, dy1 * dy1);
                float r0 = __builtin_amdgcn_sqrtf(d20); // exact trans
                float r1 = __builtin_amdgcn_sqrtf(d21);
                acc0 = fmaf(w.x, fast_exp2_neg(r0), acc0);
                acc1 = fmaf(w.y, fast_exp2_neg(r1), acc1);
            }
            acc = acc0 + acc1;
            float egi = __expf(gamma[i]);
            if (a == b) {
                // subtract diag through the SAME approximant so it cancels
                acc -= egi * fast_exp2_neg(1.41421356e-6f * LOG2E);
            }
            acc *= egi;
        }
        blockw = (a == b) ? -0.5f : -1.0f;
    } else {
        // ---- edge role (latency-bound L2 gathers; exact trans) ----
        const long base = ((long)bx * TB + threadIdx.x) * EPT;
        if (base + EPT <= e) {
            #pragma unroll
            for (int q = 0; q < EPT / 4; ++q) {
                int4 ia = *(const int4*)(ei + base + 4 * q);
                int4 ja = *(const int4*)(ej + base + 4 * q);
                const int as[4] = {ia.x, ia.y, ia.z, ia.w};
                const int bs[4] = {ja.x, ja.y, ja.z, ja.w};
                #pragma unroll
                for (int k = 0; k < 4; ++k) {
                    float2 za = Z[as[k]], zb = Z[bs[k]];
                    float dx = za.x - zb.x + EPS;
                    float dy = za.y - zb.y + EPS;
                    float r = __builtin_amdgcn_sqrtf(fmaf(dx, dx, dy * dy));
                    acc += gamma[as[k]] + gamma[bs[k]] - r;
                }
            }
        } else {
            for (int k = 0; k < EPT; ++k) {
                long idx = base + k;
                if (idx < e) {
                    int ai = ei[idx], bi = ej[idx];
                    float2 za = Z[ai], zb = Z[bi];
                    float dx = za.x - zb.x + EPS;
                    float dy = za.y - zb.y + EPS;
                    float r = __builtin_amdgcn_sqrtf(fmaf(dx, dx, dy * dy));
                    acc += gamma[ai] + gamma[bi] - r;
                }
            }
        }
        blockw = 1.f;
    }

    // fixed-order deterministic block reduction
    for (int off = 32; off > 0; off >>= 1) acc += __shfl_down(acc, off, 64);
    const int lane = threadIdx.x & 63, w = threadIdx.x >> 6;
    if (lane == 0) wsum[w] = acc;
    __syncthreads();
    if (threadIdx.x == 0) {
        float s = 0.f;
        #pragma unroll
        for (int k = 0; k < TB / 64; ++k) s += wsum[k];
        part[bx] = blockw * s;
    }
}

// Final: out[0] = sum(part) in fp64. 256 threads -> 4 coalesced rounds of
// independent loads (vs 15 with 64 thr), LDS tree, fixed order (deterministic).
__global__ void __launch_bounds__(256) k_final(
    const float* __restrict__ part, int np, float* __restrict__ out)
{
    double sd = 0.0;
    #pragma unroll 4
    for (int t = threadIdx.x; t < np; t += 256) sd += (double)part[t];
    __shared__ double sh[256];
    sh[threadIdx.x] = sd;
    __syncthreads();
    for (int s = 128; s > 0; s >>= 1) {
        if (threadIdx.x < s) sh[threadIdx.x] += sh[threadIdx.x + s];
        __syncthreads();
    }
    if (threadIdx.x == 0) out[0] = (float)sh[0];
}

extern "C" void kernel_launch(void* const* d_in, const int* in_sizes, int n_in,
                              void* d_out, int out_size, void* d_ws, size_t ws_size,
                              hipStream_t stream)
{
    const float2* Z     = (const float2*)d_in[0];
    const float*  gamma = (const float*)d_in[1];
    const int*    ei    = (const int*)d_in[2];
    const int*    ej    = (const int*)d_in[3];
    const int n = in_sizes[1];
    const int e = in_sizes[2];
    float* out = (float*)d_out;

    const int nb = (n + TD - 1) / TD;
    const int nd = nb * (nb + 1) / 2;
    const int ne = (e + TB * EPT - 1) / (TB * EPT);
    const int np = ne + nd;

    float* part = (float*)d_ws;

    hipLaunchKernelGGL(k_fused, dim3(np), dim3(TB), 0, stream,
                       Z, gamma, ei, ej, part, n, nb, ne, e);
    hipLaunchKernelGGL(k_final, dim3(1), dim3(256), 0, stream,
                       part, np, out);
}